// Round 11
// baseline (49.067 us; speedup 1.0000x reference)
//
#include <hip/hip_runtime.h>
#include <hip/hip_bf16.h>

typedef __attribute__((ext_vector_type(8))) short bf16x8;   // 8 bf16 (4 VGPRs)
typedef __attribute__((ext_vector_type(4))) float f32x4;    // MFMA accumulator

#define CA_EPS 1e-6f

__device__ __forceinline__ unsigned short f2bf(float f) {
  // round-to-nearest-even bf16
  unsigned u = __float_as_uint(f);
  u += 0x7fffu + ((u >> 16) & 1u);
  return (unsigned short)(u >> 16);
}

// Gate + L2-normalize each 128-float row, emit bf16. One launch covers both
// X (blocks [0, rowsX/8)) and Y (blocks above) -- 8 rows per 256-thread block,
// so the X/Y split is block-uniform (no divergence).
__global__ void __launch_bounds__(256) gate_norm_kernel(
    const float* __restrict__ X, const float* __restrict__ A1,
    const float* __restrict__ Y, const float* __restrict__ A2,
    unsigned short* __restrict__ outX, unsigned short* __restrict__ outY,
    int rowsX) {
  int row = (int)((blockIdx.x * 256 + threadIdx.x) >> 5);
  int l = threadIdx.x & 31;
  const float* src;
  const float* gate;
  unsigned short* dst;
  if (row < rowsX) {
    src = X; gate = A1; dst = outX;
  } else {
    src = Y; gate = A2; dst = outY; row -= rowsX;
  }
  const float4 x = *(const float4*)(src + (size_t)row * 128 + l * 4);
  const float4 a = *(const float4*)(gate + (size_t)row * 128 + l * 4);
  float g0 = x.x * a.x, g1 = x.y * a.y, g2 = x.z * a.z, g3 = x.w * a.w;
  float ss = g0 * g0 + g1 * g1 + g2 * g2 + g3 * g3;
#pragma unroll
  for (int off = 16; off; off >>= 1) ss += __shfl_xor(ss, off);
  float inv = 1.0f / sqrtf(fmaxf(ss, CA_EPS));
  ushort4 o;
  o.x = f2bf(g0 * inv);
  o.y = f2bf(g1 * inv);
  o.z = f2bf(g2 * inv);
  o.w = f2bf(g3 * inv);
  *(ushort4*)(dst + (size_t)row * 128 + l * 4) = o;
}

#define GLOAD_LDS16(g, l)                                        \
  __builtin_amdgcn_global_load_lds(                              \
      (const __attribute__((address_space(1))) void*)(g),        \
      (__attribute__((address_space(3))) void*)(l), 16, 0, 0)

// R7 structure (proven best: XCD = batch = id&7, 64x256 tile, 8 waves,
// swizzled global_load_lds staging, 80 KB LDS, 2 blocks/CU) with ONE change:
// C stores are NONTEMPORAL (nt flag -> no L2 write-allocate). Mechanism under
// test: the 16.8 MB/XCD C-write stream was evicting the 2.1 MB XCD-local
// operand set from the 4 MB L2 (the locality R7's swizzle created), coupling
// the store drain to the operand read path. nt stores stream past L2.
__global__ void __launch_bounds__(512, 4) cosine_gemm_kernel(
    const unsigned short* __restrict__ Xn,  // (B, 2048, 128) bf16
    const unsigned short* __restrict__ Yn,  // (B, 2048, 128) bf16
    float* __restrict__ C) {                // (B, 2048, 2048) f32
  __shared__ unsigned short ldsA[64 * 128];    // 16 KB
  __shared__ unsigned short ldsB[256 * 128];   // 64 KB

  const int tid = threadIdx.x;
  const int lane = tid & 63;
  const int w = tid >> 6;  // wave 0..7 = column slab (32 cols each)

  // XCD-major decomposition: XCD = batch, panels within batch stay local.
  const int id = blockIdx.x;
  const int b = id & 7;        // batch == XCD (round-robin dispatch)
  const int p = id >> 3;       // 256 panel tiles per batch
  const int tn = p & 31;       // 64-row slab of X / C rows (32 tiles)
  const int tm = p >> 5;       // 256-col slab of Y / C cols (8 tiles)

  // Tiles span the full row dimension (d=128) -> contiguous global blocks.
  const unsigned short* Asrc = Xn + ((size_t)b * 2048 + (size_t)tn * 64) * 128;
  const unsigned short* Bsrc = Yn + ((size_t)b * 2048 + (size_t)tm * 256) * 128;

  // Stage A: 1024 16B-chunks (2/thread); B: 4096 chunks (8/thread).
  // LDS dest linear (wave-uniform base + lane*16); global source chunk is
  // inverse-swizzled so LDS chunk p holds global chunk (p ^ (row&7)).
#pragma unroll
  for (int i = 0; i < 2; ++i) {
    int pp = i * 512 + tid;
    int q = (pp & ~15) | ((pp & 15) ^ ((pp >> 4) & 7));
    GLOAD_LDS16(Asrc + (size_t)q * 8, &ldsA[(i * 512 + w * 64) * 8]);
  }
#pragma unroll
  for (int i = 0; i < 8; ++i) {
    int pp = i * 512 + tid;
    int q = (pp & ~15) | ((pp & 15) ^ ((pp >> 4) & 7));
    GLOAD_LDS16(Bsrc + (size_t)q * 8, &ldsB[(i * 512 + w * 64) * 8]);
  }
  __syncthreads();

  f32x4 acc[4][2] = {};
  const int r16 = lane & 15;  // frag row (A) / frag col (B,C)
  const int kq = lane >> 4;   // k-quarter 0..3

#pragma unroll
  for (int kk = 0; kk < 4; ++kk) {
    const int kc = kk * 4 + kq;  // 8-element K-chunk index (0..15)
    bf16x8 af[4], bfr[2];
#pragma unroll
    for (int mi = 0; mi < 4; ++mi) {
      int r = mi * 16 + r16;  // A row 0..63
      af[mi] = *(const bf16x8*)(&ldsA[r * 128 + ((kc ^ (r & 7)) * 8)]);
    }
#pragma unroll
    for (int ni = 0; ni < 2; ++ni) {
      int r = w * 32 + ni * 16 + r16;  // B row 0..255
      bfr[ni] = *(const bf16x8*)(&ldsB[r * 128 + ((kc ^ (r & 7)) * 8)]);
    }
#pragma unroll
    for (int mi = 0; mi < 4; ++mi)
#pragma unroll
      for (int ni = 0; ni < 2; ++ni)
        acc[mi][ni] = __builtin_amdgcn_mfma_f32_16x16x32_bf16(
            af[mi], bfr[ni], acc[mi][ni], 0, 0, 0);
  }

  // C/D layout (m89-verified): col = lane&15, row = (lane>>4)*4 + reg.
  // NONTEMPORAL stores: bypass L2 allocation, keep operand panels resident.
  float* Cb = C + ((size_t)b * 2048 + (size_t)tn * 64) * 2048 +
              (size_t)tm * 256 + w * 32;
#pragma unroll
  for (int mi = 0; mi < 4; ++mi) {
#pragma unroll
    for (int j = 0; j < 4; ++j) {
      float* crow = Cb + (size_t)(mi * 16 + kq * 4 + j) * 2048 + r16;
#pragma unroll
      for (int ni = 0; ni < 2; ++ni)
        __builtin_nontemporal_store(acc[mi][ni][j], crow + ni * 16);
    }
  }
}

extern "C" void kernel_launch(void* const* d_in, const int* in_sizes, int n_in,
                              void* d_out, int out_size, void* d_ws, size_t ws_size,
                              hipStream_t stream) {
  const float* X  = (const float*)d_in[0];
  const float* Y  = (const float*)d_in[1];
  const float* A1 = (const float*)d_in[2];
  const float* A2 = (const float*)d_in[3];
  float* C = (float*)d_out;

  const int B = 8, N = 2048, M = 2048, D = 128;

  unsigned short* Xn = (unsigned short*)d_ws;    // (B,N,128) bf16
  unsigned short* Yn = Xn + (size_t)B * N * D;   // (B,M,128) bf16

  const int rowsX = B * N, rowsY = B * M;
  gate_norm_kernel<<<dim3((rowsX + rowsY) / 8), dim3(256), 0, stream>>>(
      X, A1, Y, A2, Xn, Yn, rowsX);
  // 1D grid: 2048 blocks, XCD = id & 7 = batch.
  cosine_gemm_kernel<<<dim3((N / 64) * (M / 256) * B), dim3(512), 0, stream>>>(
      Xn, Yn, C);
}

// Round 12
// 38.108 us; speedup vs baseline: 1.2876x; 1.2876x over previous
//
#include <hip/hip_runtime.h>
#include <hip/hip_bf16.h>

typedef __attribute__((ext_vector_type(8))) short bf16x8;   // 8 bf16 (4 VGPRs)
typedef __attribute__((ext_vector_type(4))) float f32x4;    // MFMA accumulator

#define CA_EPS 1e-6f

__device__ __forceinline__ unsigned short f2bf(float f) {
  // round-to-nearest-even bf16
  unsigned u = __float_as_uint(f);
  u += 0x7fffu + ((u >> 16) & 1u);
  return (unsigned short)(u >> 16);
}

// Gate + L2-normalize each 128-float row, emit bf16. One launch covers both
// X (blocks [0, rowsX/8)) and Y (blocks above) -- 8 rows per 256-thread block,
// so the X/Y split is block-uniform (no divergence).
__global__ void __launch_bounds__(256) gate_norm_kernel(
    const float* __restrict__ X, const float* __restrict__ A1,
    const float* __restrict__ Y, const float* __restrict__ A2,
    unsigned short* __restrict__ outX, unsigned short* __restrict__ outY,
    int rowsX) {
  int row = (int)((blockIdx.x * 256 + threadIdx.x) >> 5);
  int l = threadIdx.x & 31;
  const float* src;
  const float* gate;
  unsigned short* dst;
  if (row < rowsX) {
    src = X; gate = A1; dst = outX;
  } else {
    src = Y; gate = A2; dst = outY; row -= rowsX;
  }
  const float4 x = *(const float4*)(src + (size_t)row * 128 + l * 4);
  const float4 a = *(const float4*)(gate + (size_t)row * 128 + l * 4);
  float g0 = x.x * a.x, g1 = x.y * a.y, g2 = x.z * a.z, g3 = x.w * a.w;
  float ss = g0 * g0 + g1 * g1 + g2 * g2 + g3 * g3;
#pragma unroll
  for (int off = 16; off; off >>= 1) ss += __shfl_xor(ss, off);
  float inv = 1.0f / sqrtf(fmaxf(ss, CA_EPS));
  ushort4 o;
  o.x = f2bf(g0 * inv);
  o.y = f2bf(g1 * inv);
  o.z = f2bf(g2 * inv);
  o.w = f2bf(g3 * inv);
  *(ushort4*)(dst + (size_t)row * 128 + l * 4) = o;
}

#define GLOAD_LDS16(g, l)                                        \
  __builtin_amdgcn_global_load_lds(                              \
      (const __attribute__((address_space(1))) void*)(g),        \
      (__attribute__((address_space(3))) void*)(l), 16, 0, 0)

// C[b][n][m] = sum_k Xn[b][n][k] * Yn[b][m][k]  (bf16, row-major, K=128 whole row)
// R7 configuration -- best measured (38.0 us):
//  - 64 rows x 256 cols per block; 8 waves (1x8 wave grid, 64x32 slab each)
//  - LDS 80 KB (A 16 KB + B 64 KB), 2 blocks/CU
//  - 1D grid, XCD-major swizzle: XCD = batch (id & 7) -> each XCD's 4 MB L2
//    holds its batch's whole operand set (2.1 MB bf16); operand re-reads are
//    local L2 hits. nwg = 2048 % 8 == 0 -> bijective mapping.
//  - LDS XOR-swizzled (chunk ^= row&7) via pre-swizzled global source
//    (rule #21) -> bank-conflict-free stride-256B ds_read_b128 fragments.
//  - Plain dword C stores (L2 write-allocate path; nt measured -11 us worse).
__global__ void __launch_bounds__(512, 4) cosine_gemm_kernel(
    const unsigned short* __restrict__ Xn,  // (B, 2048, 128) bf16
    const unsigned short* __restrict__ Yn,  // (B, 2048, 128) bf16
    float* __restrict__ C) {                // (B, 2048, 2048) f32
  __shared__ unsigned short ldsA[64 * 128];    // 16 KB
  __shared__ unsigned short ldsB[256 * 128];   // 64 KB

  const int tid = threadIdx.x;
  const int lane = tid & 63;
  const int w = tid >> 6;  // wave 0..7 = column slab (32 cols each)

  // XCD-major decomposition: XCD = batch, panels within batch stay local.
  const int id = blockIdx.x;
  const int b = id & 7;        // batch == XCD (round-robin dispatch)
  const int p = id >> 3;       // 256 panel tiles per batch
  const int tn = p & 31;       // 64-row slab of X / C rows (32 tiles)
  const int tm = p >> 5;       // 256-col slab of Y / C cols (8 tiles)

  // Tiles span the full row dimension (d=128) -> contiguous global blocks.
  const unsigned short* Asrc = Xn + ((size_t)b * 2048 + (size_t)tn * 64) * 128;
  const unsigned short* Bsrc = Yn + ((size_t)b * 2048 + (size_t)tm * 256) * 128;

  // Stage A: 1024 16B-chunks (2/thread); B: 4096 chunks (8/thread).
  // LDS dest linear (wave-uniform base + lane*16); global source chunk is
  // inverse-swizzled so LDS chunk p holds global chunk (p ^ (row&7)).
#pragma unroll
  for (int i = 0; i < 2; ++i) {
    int pp = i * 512 + tid;
    int q = (pp & ~15) | ((pp & 15) ^ ((pp >> 4) & 7));
    GLOAD_LDS16(Asrc + (size_t)q * 8, &ldsA[(i * 512 + w * 64) * 8]);
  }
#pragma unroll
  for (int i = 0; i < 8; ++i) {
    int pp = i * 512 + tid;
    int q = (pp & ~15) | ((pp & 15) ^ ((pp >> 4) & 7));
    GLOAD_LDS16(Bsrc + (size_t)q * 8, &ldsB[(i * 512 + w * 64) * 8]);
  }
  __syncthreads();

  f32x4 acc[4][2] = {};
  const int r16 = lane & 15;  // frag row (A) / frag col (B,C)
  const int kq = lane >> 4;   // k-quarter 0..3

#pragma unroll
  for (int kk = 0; kk < 4; ++kk) {
    const int kc = kk * 4 + kq;  // 8-element K-chunk index (0..15)
    bf16x8 af[4], bfr[2];
#pragma unroll
    for (int mi = 0; mi < 4; ++mi) {
      int r = mi * 16 + r16;  // A row 0..63
      af[mi] = *(const bf16x8*)(&ldsA[r * 128 + ((kc ^ (r & 7)) * 8)]);
    }
#pragma unroll
    for (int ni = 0; ni < 2; ++ni) {
      int r = w * 32 + ni * 16 + r16;  // B row 0..255
      bfr[ni] = *(const bf16x8*)(&ldsB[r * 128 + ((kc ^ (r & 7)) * 8)]);
    }
#pragma unroll
    for (int mi = 0; mi < 4; ++mi)
#pragma unroll
      for (int ni = 0; ni < 2; ++ni)
        acc[mi][ni] = __builtin_amdgcn_mfma_f32_16x16x32_bf16(
            af[mi], bfr[ni], acc[mi][ni], 0, 0, 0);
  }

  // C/D layout (m89-verified): col = lane&15, row = (lane>>4)*4 + reg.
  float* Cb = C + ((size_t)b * 2048 + (size_t)tn * 64) * 2048 +
              (size_t)tm * 256 + w * 32;
#pragma unroll
  for (int mi = 0; mi < 4; ++mi) {
#pragma unroll
    for (int j = 0; j < 4; ++j) {
      float* crow = Cb + (size_t)(mi * 16 + kq * 4 + j) * 2048 + r16;
#pragma unroll
      for (int ni = 0; ni < 2; ++ni) crow[ni * 16] = acc[mi][ni][j];
    }
  }
}

extern "C" void kernel_launch(void* const* d_in, const int* in_sizes, int n_in,
                              void* d_out, int out_size, void* d_ws, size_t ws_size,
                              hipStream_t stream) {
  const float* X  = (const float*)d_in[0];
  const float* Y  = (const float*)d_in[1];
  const float* A1 = (const float*)d_in[2];
  const float* A2 = (const float*)d_in[3];
  float* C = (float*)d_out;

  const int B = 8, N = 2048, M = 2048, D = 128;

  unsigned short* Xn = (unsigned short*)d_ws;    // (B,N,128) bf16
  unsigned short* Yn = Xn + (size_t)B * N * D;   // (B,M,128) bf16

  const int rowsX = B * N, rowsY = B * M;
  gate_norm_kernel<<<dim3((rowsX + rowsY) / 8), dim3(256), 0, stream>>>(
      X, A1, Y, A2, Xn, Yn, rowsX);
  // 1D grid: 2048 blocks, XCD = id & 7 = batch.
  cosine_gemm_kernel<<<dim3((N / 64) * (M / 256) * B), dim3(512), 0, stream>>>(
      Xn, Yn, C);
}